// Round 1
// baseline (497.951 us; speedup 1.0000x reference)
//
#include <hip/hip_runtime.h>

// BilinearResNet fused forward.
// Shapes: x[65536,784] @ W_embed.T[784,16] -> h_x[65536,16]
//         4x bilinear blocks: u=h@L^T[16,6], v=h@R^T, h=u*v, h_x += h@D^T[6,16]
//         logits = h_x @ W_head.T[16,10]
// Outputs concat flat: logits[65536*10], h1..h4[65536*6 each]. All fp32.
//
// Strategy: memory-bound on reading x (205.5 MB). One thread per row, float4
// row reads (64B-line aligned per lane), weights via wave-uniform scalar
// loads, entire chain in registers, single kernel.

#define IN_DIM   784
#define D_MODEL  16
#define HIDDEN   6
#define N_BLOCKS 4
#define N_CLS    10
#define BATCH    65536

__global__ __launch_bounds__(128) void bilinear_resnet_fused(
    const float* __restrict__ x,
    const float* __restrict__ W_embed,   // [16][784]
    const float* __restrict__ L_w,       // [4][6][16]
    const float* __restrict__ R_w,       // [4][6][16]
    const float* __restrict__ D_w,       // [4][16][6]
    const float* __restrict__ W_head,    // [10][16]
    float* __restrict__ out)
{
    const int row = blockIdx.x * blockDim.x + threadIdx.x;
    const float4* xr = reinterpret_cast<const float4*>(x + (size_t)row * IN_DIM);

    float acc[D_MODEL];
#pragma unroll
    for (int d = 0; d < D_MODEL; ++d) acc[d] = 0.f;

    // ---- embed: h_x = x @ W_embed^T, chunks of 16 floats with prefetch ----
    constexpr int NCH = IN_DIM / 16;   // 49 chunks
    float4 cur[4], nxt[4];
#pragma unroll
    for (int q = 0; q < 4; ++q) cur[q] = xr[q];

    for (int ch = 0; ch < NCH; ++ch) {
        if (ch + 1 < NCH) {
#pragma unroll
            for (int q = 0; q < 4; ++q) nxt[q] = xr[(ch + 1) * 4 + q];
        }
        float xs[16];
#pragma unroll
        for (int q = 0; q < 4; ++q) {
            xs[4 * q + 0] = cur[q].x;
            xs[4 * q + 1] = cur[q].y;
            xs[4 * q + 2] = cur[q].z;
            xs[4 * q + 3] = cur[q].w;
        }
        const float* wbase = W_embed + ch * 16;  // uniform address
#pragma unroll
        for (int d = 0; d < D_MODEL; ++d) {
            const float* wd = wbase + d * IN_DIM;  // 16 contiguous, 64B-aligned
            float s = acc[d];
#pragma unroll
            for (int j = 0; j < 16; ++j) s = fmaf(xs[j], wd[j], s);
            acc[d] = s;
        }
#pragma unroll
        for (int q = 0; q < 4; ++q) cur[q] = nxt[q];
    }

    // ---- bilinear residual blocks ----
#pragma unroll
    for (int b = 0; b < N_BLOCKS; ++b) {
        const float* Lb = L_w + b * HIDDEN * D_MODEL;
        const float* Rb = R_w + b * HIDDEN * D_MODEL;
        const float* Db = D_w + b * D_MODEL * HIDDEN;
        float h[HIDDEN];
#pragma unroll
        for (int j = 0; j < HIDDEN; ++j) {
            float u = 0.f, v = 0.f;
#pragma unroll
            for (int d = 0; d < D_MODEL; ++d) {
                u = fmaf(acc[d], Lb[j * D_MODEL + d], u);
                v = fmaf(acc[d], Rb[j * D_MODEL + d], v);
            }
            h[j] = u * v;
        }
#pragma unroll
        for (int d = 0; d < D_MODEL; ++d) {
            float s = acc[d];
#pragma unroll
            for (int j = 0; j < HIDDEN; ++j) s = fmaf(h[j], Db[d * HIDDEN + j], s);
            acc[d] = s;
        }
        // h_i output: offset = 10*B + b*6*B + row*6
        float* hout = out + (size_t)N_CLS * BATCH + (size_t)b * HIDDEN * BATCH
                      + (size_t)row * HIDDEN;
#pragma unroll
        for (int j = 0; j < HIDDEN; ++j) hout[j] = h[j];
    }

    // ---- head ----
    float* lout = out + (size_t)row * N_CLS;
#pragma unroll
    for (int k = 0; k < N_CLS; ++k) {
        float s = 0.f;
#pragma unroll
        for (int d = 0; d < D_MODEL; ++d) s = fmaf(acc[d], W_head[k * D_MODEL + d], s);
        lout[k] = s;
    }
}

extern "C" void kernel_launch(void* const* d_in, const int* in_sizes, int n_in,
                              void* d_out, int out_size, void* d_ws, size_t ws_size,
                              hipStream_t stream) {
    const float* x       = (const float*)d_in[0];
    const float* W_embed = (const float*)d_in[1];
    const float* L_w     = (const float*)d_in[2];
    const float* R_w     = (const float*)d_in[3];
    const float* D_w     = (const float*)d_in[4];
    const float* W_head  = (const float*)d_in[5];
    float* out = (float*)d_out;

    const int block = 128;
    const int grid = BATCH / block;  // 512 blocks
    bilinear_resnet_fused<<<grid, block, 0, stream>>>(
        x, W_embed, L_w, R_w, D_w, W_head, out);
}

// Round 2
// 354.179 us; speedup vs baseline: 1.4059x; 1.4059x over previous
//
#include <hip/hip_runtime.h>

// BilinearResNet fused forward, round 2.
// Layout: 1024 blocks x 256 threads. Each block owns 64 rows.
// The 4 waves of a block each handle a 196-float K-segment of the embed GEMM
// (wave-uniform weight addresses -> s_load + SGPR-broadcast FMA, no per-lane
// weight traffic). Partial acc[16] reduced via LDS; wave 0 runs the bilinear
// chain + stores. 4096 waves total = 16 waves/CU (vs 4 in round 1, which was
// latency-bound at 12% occupancy / 14% VALUBusy).

#define IN_DIM   784
#define D_MODEL  16
#define HIDDEN   6
#define N_BLOCKS 4
#define N_CLS    10
#define BATCH    65536
#define SEG      196   // IN_DIM / 4 floats per wave segment
#define NIT      49    // SEG / 4 float4 iterations

__global__ __launch_bounds__(256, 4) void bilinear_resnet_fused(
    const float* __restrict__ x,
    const float* __restrict__ W_embed,   // [16][784]
    const float* __restrict__ L_w,       // [4][6][16]
    const float* __restrict__ R_w,       // [4][6][16]
    const float* __restrict__ D_w,       // [4][16][6]
    const float* __restrict__ W_head,    // [10][16]
    float* __restrict__ out)
{
    __shared__ float parts[3][64][17];   // stride 17: bank-conflict-free

    const int tid  = threadIdx.x;
    const int lane = tid & 63;
    // wave id is uniform by construction; readfirstlane forces the compiler
    // to treat it (and everything derived) as SGPR -> scalar weight loads.
    const int wv   = __builtin_amdgcn_readfirstlane(tid >> 6);  // 0..3
    const int row  = blockIdx.x * 64 + lane;

    const float4* xr = reinterpret_cast<const float4*>(
        x + (size_t)row * IN_DIM + wv * SEG);
    const float* wseg = W_embed + wv * SEG;  // uniform base

    float acc[D_MODEL];
#pragma unroll
    for (int d = 0; d < D_MODEL; ++d) acc[d] = 0.f;

    // ---- embed partial: acc[d] += sum_k x[row][seg+k] * W[d][seg+k] ----
    float4 cur = xr[0];
    for (int it = 0; it < NIT; ++it) {
        float4 nxt = make_float4(0.f, 0.f, 0.f, 0.f);
        if (it + 1 < NIT) nxt = xr[it + 1];
        const float* wk = wseg + it * 4;   // uniform
#pragma unroll
        for (int d = 0; d < D_MODEL; ++d) {
            const float* wd = wk + d * IN_DIM;  // uniform -> s_load_dwordx4
            float s = acc[d];
            s = fmaf(cur.x, wd[0], s);
            s = fmaf(cur.y, wd[1], s);
            s = fmaf(cur.z, wd[2], s);
            s = fmaf(cur.w, wd[3], s);
            acc[d] = s;
        }
        cur = nxt;
    }

    // ---- reduce the 4 wave-partials for each row ----
    if (wv != 0) {
#pragma unroll
        for (int d = 0; d < D_MODEL; ++d) parts[wv - 1][lane][d] = acc[d];
    }
    __syncthreads();
    if (wv != 0) return;

#pragma unroll
    for (int d = 0; d < D_MODEL; ++d)
        acc[d] += parts[0][lane][d] + parts[1][lane][d] + parts[2][lane][d];

    // ---- bilinear residual blocks (wave 0 only; weights uniform->scalar) ----
#pragma unroll
    for (int b = 0; b < N_BLOCKS; ++b) {
        const float* Lb = L_w + b * HIDDEN * D_MODEL;
        const float* Rb = R_w + b * HIDDEN * D_MODEL;
        const float* Db = D_w + b * D_MODEL * HIDDEN;
        float h[HIDDEN];
#pragma unroll
        for (int j = 0; j < HIDDEN; ++j) {
            float u = 0.f, v = 0.f;
#pragma unroll
            for (int d = 0; d < D_MODEL; ++d) {
                u = fmaf(acc[d], Lb[j * D_MODEL + d], u);
                v = fmaf(acc[d], Rb[j * D_MODEL + d], v);
            }
            h[j] = u * v;
        }
#pragma unroll
        for (int d = 0; d < D_MODEL; ++d) {
            float s = acc[d];
#pragma unroll
            for (int j = 0; j < HIDDEN; ++j) s = fmaf(h[j], Db[d * HIDDEN + j], s);
            acc[d] = s;
        }
        float* hout = out + (size_t)N_CLS * BATCH + (size_t)b * HIDDEN * BATCH
                      + (size_t)row * HIDDEN;
#pragma unroll
        for (int j = 0; j < HIDDEN; ++j) hout[j] = h[j];
    }

    // ---- head ----
    float* lout = out + (size_t)row * N_CLS;
#pragma unroll
    for (int k = 0; k < N_CLS; ++k) {
        float s = 0.f;
#pragma unroll
        for (int d = 0; d < D_MODEL; ++d) s = fmaf(acc[d], W_head[k * D_MODEL + d], s);
        lout[k] = s;
    }
}

extern "C" void kernel_launch(void* const* d_in, const int* in_sizes, int n_in,
                              void* d_out, int out_size, void* d_ws, size_t ws_size,
                              hipStream_t stream) {
    const float* x       = (const float*)d_in[0];
    const float* W_embed = (const float*)d_in[1];
    const float* L_w     = (const float*)d_in[2];
    const float* R_w     = (const float*)d_in[3];
    const float* D_w     = (const float*)d_in[4];
    const float* W_head  = (const float*)d_in[5];
    float* out = (float*)d_out;

    const int grid = BATCH / 64;   // 1024 blocks, 64 rows each
    bilinear_resnet_fused<<<grid, 256, 0, stream>>>(
        x, W_embed, L_w, R_w, D_w, W_head, out);
}